// Round 1
// baseline (925.870 us; speedup 1.0000x reference)
//
#include <hip/hip_runtime.h>
#include <cstdint>
#include <cstddef>

// ---------------------------------------------------------------------------
// Net_25950192402497: 2-layer MLP-message GNN + link-prediction head.
// Key identity: segment_sum(concat(x_i,x_j,ef)@W + b) over dst
//   = deg*(h@Wi + b) + (scatter_add h[src])@Wj + (scatter_add ef)@We
// so edge-dim GEMMs (E=500k, K=272) collapse to node-dim GEMMs (N=50k).
// ---------------------------------------------------------------------------

// Generic tiled GEMM: OUT[r, 0:128] (+)= act( scale[r] * (X[r,0:K] @ W[K,128] + bias) )
// flags bit0: accumulate into OUT; bit1: relu.
// K must be a power of two <= 128 (here 128 or 16); kshift = log2(K).
__launch_bounds__(256)
__global__ void gemm_tiled(const float* __restrict__ X, const float* __restrict__ W,
                           const float* __restrict__ bias, const float* __restrict__ rowscale,
                           float* __restrict__ OUT, int Nrows, int K, int kshift, int flags)
{
    __shared__ float ws[64 * 128];   // 32 KB: K-tile of W
    __shared__ float xs[32 * 128];   // 16 KB: 32 staged input rows
    const int tid = threadIdx.x;
    const int c  = tid & 31;         // column quad: cols 4c..4c+3
    const int rg = tid >> 5;         // row group: rows 4rg..4rg+3
    const int row0 = blockIdx.x << 5;

    // stage 32 rows of X
    const int total = K << 5;
    for (int idx = tid; idx < total; idx += 256) {
        const int r = idx >> kshift;
        const int k = idx & (K - 1);
        const int gr = row0 + r;
        xs[(r << kshift) + k] = (gr < Nrows) ? X[(size_t)gr * K + k] : 0.0f;
    }

    float acc[4][4];
#pragma unroll
    for (int i = 0; i < 4; ++i)
#pragma unroll
        for (int j = 0; j < 4; ++j) acc[i][j] = 0.0f;

    for (int kt = 0; kt < K; kt += 64) {
        const int KT = min(64, K - kt);
        __syncthreads();
        for (int idx = tid; idx < (KT << 7); idx += 256)
            ws[idx] = W[((size_t)kt << 7) + idx];
        __syncthreads();
        for (int k = 0; k < KT; k += 4) {
            const float4 w0 = *(const float4*)&ws[((k + 0) << 7) + (c << 2)];
            const float4 w1 = *(const float4*)&ws[((k + 1) << 7) + (c << 2)];
            const float4 w2 = *(const float4*)&ws[((k + 2) << 7) + (c << 2)];
            const float4 w3 = *(const float4*)&ws[((k + 3) << 7) + (c << 2)];
#pragma unroll
            for (int i = 0; i < 4; ++i) {
                const int r = (rg << 2) + i;
                const float4 xq = *(const float4*)&xs[(r << kshift) + kt + k];
                acc[i][0] += xq.x * w0.x + xq.y * w1.x + xq.z * w2.x + xq.w * w3.x;
                acc[i][1] += xq.x * w0.y + xq.y * w1.y + xq.z * w2.y + xq.w * w3.y;
                acc[i][2] += xq.x * w0.z + xq.y * w1.z + xq.z * w2.z + xq.w * w3.z;
                acc[i][3] += xq.x * w0.w + xq.y * w1.w + xq.z * w2.w + xq.w * w3.w;
            }
        }
    }

#pragma unroll
    for (int i = 0; i < 4; ++i) {
        const int r = row0 + (rg << 2) + i;
        if (r >= Nrows) continue;
        float4 v = make_float4(acc[i][0], acc[i][1], acc[i][2], acc[i][3]);
        if (bias) {
            const float4 bq = *(const float4*)&bias[c << 2];
            v.x += bq.x; v.y += bq.y; v.z += bq.z; v.w += bq.w;
        }
        if (rowscale) {
            const float s = rowscale[r];
            v.x *= s; v.y *= s; v.z *= s; v.w *= s;
        }
        float* op = OUT + ((size_t)r << 7) + (c << 2);
        if (flags & 1) {
            const float4 o = *(const float4*)op;
            v.x += o.x; v.y += o.y; v.z += o.z; v.w += o.w;
        }
        if (flags & 2) {
            v.x = fmaxf(v.x, 0.f); v.y = fmaxf(v.y, 0.f);
            v.z = fmaxf(v.z, 0.f); v.w = fmaxf(v.w, 0.f);
        }
        *(float4*)op = v;
    }
}

// agg[dst] += h[src] for every edge; one thread per (edge, feature)
__launch_bounds__(256)
__global__ void scatter_h(const int* __restrict__ ei, const float* __restrict__ h,
                          float* __restrict__ agg, int E)
{
    const long long tid = (long long)blockIdx.x * 256 + threadIdx.x;
    const int e = (int)(tid >> 7);
    if (e >= E) return;
    const int j = (int)(tid & 127);
    const int s = ei[e];
    const int d = ei[E + e];
    unsafeAtomicAdd(&agg[((size_t)d << 7) + j], h[((size_t)s << 7) + j]);
}

// aggef[dst] += ef[e]; deg[dst] += 1 — computed once, shared by both convs
__launch_bounds__(256)
__global__ void scatter_ef_deg(const int* __restrict__ ei, const float* __restrict__ ef,
                               float* __restrict__ aggef, float* __restrict__ deg, int E)
{
    const long long tid = (long long)blockIdx.x * 256 + threadIdx.x;
    const int e = (int)(tid >> 4);
    if (e >= E) return;
    const int j = (int)(tid & 15);
    const int d = ei[E + e];
    unsafeAtomicAdd(&aggef[(size_t)d * 16 + j], ef[(size_t)e * 16 + j]);
    if (j == 0) unsafeAtomicAdd(&deg[d], 1.0f);
}

// pred[q,:2] = concat(x2[a], x2[b]) @ lpW + lpb  — one wave per query
__launch_bounds__(256)
__global__ void head_kernel(const float* __restrict__ x2, const int* __restrict__ eli,
                            const float* __restrict__ lpW, const float* __restrict__ lpb,
                            float* __restrict__ out, int Q)
{
    const long long gt = (long long)blockIdx.x * 256 + threadIdx.x;
    const int q = (int)(gt >> 6);
    if (q >= Q) return;
    const int lane = threadIdx.x & 63;
    const int a = eli[q];
    const int b = eli[Q + q];
    const float* rowp = (lane < 32)
        ? x2 + ((size_t)a << 7) + (lane << 2)
        : x2 + ((size_t)b << 7) + ((lane - 32) << 2);
    const float4 v = *(const float4*)rowp;
    const int k0 = lane << 2;                       // concat-dim index 0..252
    const float4 wA = *(const float4*)(lpW + (k0 << 1));      // rows k0,k0+1 (2 cols each)
    const float4 wB = *(const float4*)(lpW + (k0 << 1) + 4);  // rows k0+2,k0+3
    float c0 = v.x * wA.x + v.y * wA.z + v.z * wB.x + v.w * wB.z;
    float c1 = v.x * wA.y + v.y * wA.w + v.z * wB.y + v.w * wB.w;
#pragma unroll
    for (int off = 32; off > 0; off >>= 1) {
        c0 += __shfl_down(c0, off);
        c1 += __shfl_down(c1, off);
    }
    if (lane == 0) {
        out[(size_t)q * 2 + 0] = c0 + lpb[0];
        out[(size_t)q * 2 + 1] = c1 + lpb[1];
    }
}

__launch_bounds__(256)
__global__ void zero_f4(float4* __restrict__ p, long long n4)
{
    const long long i = (long long)blockIdx.x * 256 + threadIdx.x;
    if (i < n4) p[i] = make_float4(0.f, 0.f, 0.f, 0.f);
}

extern "C" void kernel_launch(void* const* d_in, const int* in_sizes, int n_in,
                              void* d_out, int out_size, void* d_ws, size_t ws_size,
                              hipStream_t stream)
{
    const float* nf   = (const float*)d_in[0];
    const int*   ei   = (const int*)d_in[1];
    const float* ef   = (const float*)d_in[2];
    const int*   eli  = (const int*)d_in[3];
    const float* c1pW = (const float*)d_in[4];
    const float* c1pb = (const float*)d_in[5];
    const float* c1mW = (const float*)d_in[6];
    const float* c1mb = (const float*)d_in[7];
    const float* c2pW = (const float*)d_in[8];
    const float* c2pb = (const float*)d_in[9];
    const float* c2mW = (const float*)d_in[10];
    const float* c2mb = (const float*)d_in[11];
    const float* lpW  = (const float*)d_in[12];
    const float* lpb  = (const float*)d_in[13];
    float* out = (float*)d_out;

    const int N = in_sizes[0] / 128;
    const int E = in_sizes[1] / 2;
    const int Q = in_sizes[3] / 2;

    // workspace layout: A (h), C (x), then zero-region [B (agg) | EFA | DEG]
    float* A   = (float*)d_ws;                 // N*128
    float* C   = A + (size_t)N * 128;          // N*128
    float* B   = C + (size_t)N * 128;          // N*128
    float* EFA = B + (size_t)N * 128;          // N*16
    float* DEG = EFA + (size_t)N * 16;         // N
    // total: N*401 floats = 80.2 MB for N=50000

    const int gemmGrid = (N + 31) / 32;
    const int scatGrid = (int)(((long long)E * 128 + 255) / 256);
    const int efGrid   = (int)(((long long)E * 16 + 255) / 256);
    const int headGrid = (int)(((long long)Q * 64 + 255) / 256);

    // zero B + EFA + DEG (contiguous: N*(128+16+1) floats)
    {
        const long long n4 = ((long long)N * 145) / 4;
        zero_f4<<<(int)((n4 + 255) / 256), 256, 0, stream>>>((float4*)B, n4);
    }

    // ---- conv1 ----
    // h1 = relu(nf @ c1_pre_W + b)
    gemm_tiled<<<gemmGrid, 256, 0, stream>>>(nf, c1pW, c1pb, nullptr, A, N, 128, 7, 2);
    scatter_h<<<scatGrid, 256, 0, stream>>>(ei, A, B, E);
    scatter_ef_deg<<<efGrid, 256, 0, stream>>>(ei, ef, EFA, DEG, E);
    // x1 = relu(deg*(h1@Wi + b_msg) + agg@Wj + aggef@We)
    gemm_tiled<<<gemmGrid, 256, 0, stream>>>(B,   c1mW + 128 * 128, nullptr, nullptr, C, N, 128, 7, 0);
    gemm_tiled<<<gemmGrid, 256, 0, stream>>>(EFA, c1mW + 256 * 128, nullptr, nullptr, C, N, 16,  4, 1);
    gemm_tiled<<<gemmGrid, 256, 0, stream>>>(A,   c1mW,             c1mb,    DEG,     C, N, 128, 7, 1 | 2);

    // ---- conv2 ----
    // h2 = relu(x1 @ c2_pre_W + b)
    gemm_tiled<<<gemmGrid, 256, 0, stream>>>(C, c2pW, c2pb, nullptr, A, N, 128, 7, 2);
    {
        const long long n4 = ((long long)N * 128) / 4;
        zero_f4<<<(int)((n4 + 255) / 256), 256, 0, stream>>>((float4*)B, n4);
    }
    scatter_h<<<scatGrid, 256, 0, stream>>>(ei, A, B, E);
    // x2 = deg*(h2@Wi + b_msg) + agg@Wj + aggef@We   (no relu)
    gemm_tiled<<<gemmGrid, 256, 0, stream>>>(B,   c2mW + 128 * 128, nullptr, nullptr, C, N, 128, 7, 0);
    gemm_tiled<<<gemmGrid, 256, 0, stream>>>(EFA, c2mW + 256 * 128, nullptr, nullptr, C, N, 16,  4, 1);
    gemm_tiled<<<gemmGrid, 256, 0, stream>>>(A,   c2mW,             c2mb,    DEG,     C, N, 128, 7, 1);

    // ---- head ----
    head_kernel<<<headGrid, 256, 0, stream>>>(C, eli, lpW, lpb, out, Q);
}

// Round 2
// 742.166 us; speedup vs baseline: 1.2475x; 1.2475x over previous
//
#include <hip/hip_runtime.h>
#include <cstdint>
#include <cstddef>

// ---------------------------------------------------------------------------
// Net_25950192402497: 2-layer MLP-message GNN + link-prediction head.
// Identity: segment_sum(concat(x_i,x_j,ef)@W + b) over dst
//   = deg*(h@Wi + b) + (scatter_add h[src])@Wj + (scatter_add ef)@We
// R2: atomics-free aggregation — build dst-CSR once per launch, then
// gather-sum h[src] rows per dst node (writes 25.6MB instead of 256MB of
// uncoalesced atomic write-through; reads served by LLC-resident h).
// ---------------------------------------------------------------------------

// Generic tiled GEMM: OUT[r, 0:128] (+)= act( scale[r] * (X[r,0:K] @ W[K,128] + bias) )
// flags bit0: accumulate into OUT; bit1: relu.
// K must be a power of two <= 128 (here 128 or 16); kshift = log2(K).
__launch_bounds__(256)
__global__ void gemm_tiled(const float* __restrict__ X, const float* __restrict__ W,
                           const float* __restrict__ bias, const float* __restrict__ rowscale,
                           float* __restrict__ OUT, int Nrows, int K, int kshift, int flags)
{
    __shared__ float ws[64 * 128];   // 32 KB: K-tile of W
    __shared__ float xs[32 * 128];   // 16 KB: 32 staged input rows
    const int tid = threadIdx.x;
    const int c  = tid & 31;         // column quad: cols 4c..4c+3
    const int rg = tid >> 5;         // row group: rows 4rg..4rg+3
    const int row0 = blockIdx.x << 5;

    // stage 32 rows of X
    const int total = K << 5;
    for (int idx = tid; idx < total; idx += 256) {
        const int r = idx >> kshift;
        const int k = idx & (K - 1);
        const int gr = row0 + r;
        xs[(r << kshift) + k] = (gr < Nrows) ? X[(size_t)gr * K + k] : 0.0f;
    }

    float acc[4][4];
#pragma unroll
    for (int i = 0; i < 4; ++i)
#pragma unroll
        for (int j = 0; j < 4; ++j) acc[i][j] = 0.0f;

    for (int kt = 0; kt < K; kt += 64) {
        const int KT = min(64, K - kt);
        __syncthreads();
        for (int idx = tid; idx < (KT << 7); idx += 256)
            ws[idx] = W[((size_t)kt << 7) + idx];
        __syncthreads();
        for (int k = 0; k < KT; k += 4) {
            const float4 w0 = *(const float4*)&ws[((k + 0) << 7) + (c << 2)];
            const float4 w1 = *(const float4*)&ws[((k + 1) << 7) + (c << 2)];
            const float4 w2 = *(const float4*)&ws[((k + 2) << 7) + (c << 2)];
            const float4 w3 = *(const float4*)&ws[((k + 3) << 7) + (c << 2)];
#pragma unroll
            for (int i = 0; i < 4; ++i) {
                const int r = (rg << 2) + i;
                const float4 xq = *(const float4*)&xs[(r << kshift) + kt + k];
                acc[i][0] += xq.x * w0.x + xq.y * w1.x + xq.z * w2.x + xq.w * w3.x;
                acc[i][1] += xq.x * w0.y + xq.y * w1.y + xq.z * w2.y + xq.w * w3.y;
                acc[i][2] += xq.x * w0.z + xq.y * w1.z + xq.z * w2.z + xq.w * w3.z;
                acc[i][3] += xq.x * w0.w + xq.y * w1.w + xq.z * w2.w + xq.w * w3.w;
            }
        }
    }

#pragma unroll
    for (int i = 0; i < 4; ++i) {
        const int r = row0 + (rg << 2) + i;
        if (r >= Nrows) continue;
        float4 v = make_float4(acc[i][0], acc[i][1], acc[i][2], acc[i][3]);
        if (bias) {
            const float4 bq = *(const float4*)&bias[c << 2];
            v.x += bq.x; v.y += bq.y; v.z += bq.z; v.w += bq.w;
        }
        if (rowscale) {
            const float s = rowscale[r];
            v.x *= s; v.y *= s; v.z *= s; v.w *= s;
        }
        float* op = OUT + ((size_t)r << 7) + (c << 2);
        if (flags & 1) {
            const float4 o = *(const float4*)op;
            v.x += o.x; v.y += o.y; v.z += o.z; v.w += o.w;
        }
        if (flags & 2) {
            v.x = fmaxf(v.x, 0.f); v.y = fmaxf(v.y, 0.f);
            v.z = fmaxf(v.z, 0.f); v.w = fmaxf(v.w, 0.f);
        }
        *(float4*)op = v;
    }
}

// ---- CSR build (once per launch; edges fixed) ----

__launch_bounds__(256)
__global__ void zero_int(int* __restrict__ p, int n)
{
    const int i = blockIdx.x * 256 + threadIdx.x;
    if (i < n) p[i] = 0;
}

__launch_bounds__(256)
__global__ void hist_kernel(const int* __restrict__ ei, int* __restrict__ counts, int E)
{
    const int e = blockIdx.x * 256 + threadIdx.x;
    if (e < E) atomicAdd(&counts[ei[E + e]], 1);
}

// single-block exclusive scan of counts[N] -> rowstart[N+1]; also cursor copy
// and float degree. N=50k: each thread serial-sums a ~196-elem chunk, then
// 256-wide Hillis-Steele in LDS, then serial write-out. ~200KB traffic: cheap.
__launch_bounds__(256)
__global__ void scan_kernel(const int* __restrict__ counts, int* __restrict__ rowstart,
                            int* __restrict__ cursor, float* __restrict__ degf, int N)
{
    __shared__ int part[256];
    const int t = threadIdx.x;
    const int chunk = (N + 255) / 256;
    const int lo = t * chunk;
    const int hi = min(lo + chunk, N);
    int s = 0;
    for (int i = lo; i < hi; ++i) s += counts[i];
    part[t] = s;
    __syncthreads();
    for (int off = 1; off < 256; off <<= 1) {
        const int v = (t >= off) ? part[t - off] : 0;
        __syncthreads();
        part[t] += v;
        __syncthreads();
    }
    int run = (t == 0) ? 0 : part[t - 1];
    for (int i = lo; i < hi; ++i) {
        const int c = counts[i];
        rowstart[i] = run;
        cursor[i]   = run;
        degf[i]     = (float)c;
        run += c;
    }
    if (t == 255) rowstart[N] = run;
}

__launch_bounds__(256)
__global__ void build_elist(const int* __restrict__ ei, int* __restrict__ cursor,
                            int2* __restrict__ elist, int E)
{
    const int e = blockIdx.x * 256 + threadIdx.x;
    if (e >= E) return;
    const int d = ei[E + e];
    const int pos = atomicAdd(&cursor[d], 1);
    elist[pos] = make_int2(ei[e], e);   // (src node, edge id)
}

// ---- gather aggregations (atomic-free) ----

// agg[node] = sum over edges of h[src]; one wave per dst node, float2/lane.
__launch_bounds__(256)
__global__ void gather_h(const int2* __restrict__ elist, const int* __restrict__ rowstart,
                         const float* __restrict__ h, float* __restrict__ agg, int N)
{
    const int node = blockIdx.x * 4 + (threadIdx.x >> 6);
    if (node >= N) return;
    const int lane = threadIdx.x & 63;
    const int beg = rowstart[node];
    const int end = rowstart[node + 1];
    float2 acc = make_float2(0.f, 0.f);
    int k = beg;
    for (; k + 1 < end; k += 2) {          // unroll 2 for load-latency overlap
        const int s0 = elist[k].x;
        const int s1 = elist[k + 1].x;
        const float2 v0 = *(const float2*)&h[((size_t)s0 << 7) + (lane << 1)];
        const float2 v1 = *(const float2*)&h[((size_t)s1 << 7) + (lane << 1)];
        acc.x += v0.x + v1.x;
        acc.y += v0.y + v1.y;
    }
    if (k < end) {
        const int s = elist[k].x;
        const float2 v = *(const float2*)&h[((size_t)s << 7) + (lane << 1)];
        acc.x += v.x; acc.y += v.y;
    }
    *(float2*)&agg[((size_t)node << 7) + (lane << 1)] = acc;
}

// aggef[node] = sum over edges of ef[e]; 16 lanes per node (16 nodes/block).
__launch_bounds__(256)
__global__ void gather_ef(const int2* __restrict__ elist, const int* __restrict__ rowstart,
                          const float* __restrict__ ef, float* __restrict__ aggef, int N)
{
    const int node = blockIdx.x * 16 + (threadIdx.x >> 4);
    if (node >= N) return;
    const int lane = threadIdx.x & 15;
    const int beg = rowstart[node];
    const int end = rowstart[node + 1];
    float acc = 0.f;
    for (int k = beg; k < end; ++k) {
        const int e = elist[k].y;
        acc += ef[((size_t)e << 4) + lane];
    }
    aggef[((size_t)node << 4) + lane] = acc;
}

// pred[q,:2] = concat(x2[a], x2[b]) @ lpW + lpb  — one wave per query
__launch_bounds__(256)
__global__ void head_kernel(const float* __restrict__ x2, const int* __restrict__ eli,
                            const float* __restrict__ lpW, const float* __restrict__ lpb,
                            float* __restrict__ out, int Q)
{
    const long long gt = (long long)blockIdx.x * 256 + threadIdx.x;
    const int q = (int)(gt >> 6);
    if (q >= Q) return;
    const int lane = threadIdx.x & 63;
    const int a = eli[q];
    const int b = eli[Q + q];
    const float* rowp = (lane < 32)
        ? x2 + ((size_t)a << 7) + (lane << 2)
        : x2 + ((size_t)b << 7) + ((lane - 32) << 2);
    const float4 v = *(const float4*)rowp;
    const int k0 = lane << 2;                       // concat-dim index 0..252
    const float4 wA = *(const float4*)(lpW + (k0 << 1));      // rows k0,k0+1 (2 cols each)
    const float4 wB = *(const float4*)(lpW + (k0 << 1) + 4);  // rows k0+2,k0+3
    float c0 = v.x * wA.x + v.y * wA.z + v.z * wB.x + v.w * wB.z;
    float c1 = v.x * wA.y + v.y * wA.w + v.z * wB.y + v.w * wB.w;
#pragma unroll
    for (int off = 32; off > 0; off >>= 1) {
        c0 += __shfl_down(c0, off);
        c1 += __shfl_down(c1, off);
    }
    if (lane == 0) {
        out[(size_t)q * 2 + 0] = c0 + lpb[0];
        out[(size_t)q * 2 + 1] = c1 + lpb[1];
    }
}

extern "C" void kernel_launch(void* const* d_in, const int* in_sizes, int n_in,
                              void* d_out, int out_size, void* d_ws, size_t ws_size,
                              hipStream_t stream)
{
    const float* nf   = (const float*)d_in[0];
    const int*   ei   = (const int*)d_in[1];
    const float* ef   = (const float*)d_in[2];
    const int*   eli  = (const int*)d_in[3];
    const float* c1pW = (const float*)d_in[4];
    const float* c1pb = (const float*)d_in[5];
    const float* c1mW = (const float*)d_in[6];
    const float* c1mb = (const float*)d_in[7];
    const float* c2pW = (const float*)d_in[8];
    const float* c2pb = (const float*)d_in[9];
    const float* c2mW = (const float*)d_in[10];
    const float* c2mb = (const float*)d_in[11];
    const float* lpW  = (const float*)d_in[12];
    const float* lpb  = (const float*)d_in[13];
    float* out = (float*)d_out;

    const int N = in_sizes[0] / 128;
    const int E = in_sizes[1] / 2;
    const int Q = in_sizes[3] / 2;

    // workspace layout
    float* A   = (float*)d_ws;                 // N*128  (h)
    float* C   = A + (size_t)N * 128;          // N*128  (x accumulator)
    float* B   = C + (size_t)N * 128;          // N*128  (gathered agg)
    float* EFA = B + (size_t)N * 128;          // N*16
    float* DEG = EFA + (size_t)N * 16;         // N (float degree)
    int* counts   = (int*)(DEG + N);           // N
    int* rowstart = counts + N;                // N+1
    int* cursor   = rowstart + N + 1;          // N
    // align elist to 8 bytes
    uintptr_t ep = (uintptr_t)(cursor + N);
    ep = (ep + 7) & ~(uintptr_t)7;
    int2* elist = (int2*)ep;                   // E int2 (src, edge id)
    // total ≈ N*401*4 + N*4*~13 + E*8 ≈ 85 MB for N=50k, E=500k

    const int gemmGrid = (N + 31) / 32;
    const int eGrid    = (E + 255) / 256;
    const int ghGrid   = (N + 3) / 4;
    const int geGrid   = (N + 15) / 16;
    const int headGrid = (int)(((long long)Q * 64 + 255) / 256);

    // ---- CSR build (shared by both convs) ----
    zero_int<<<(N + 255) / 256, 256, 0, stream>>>(counts, N);
    hist_kernel<<<eGrid, 256, 0, stream>>>(ei, counts, E);
    scan_kernel<<<1, 256, 0, stream>>>(counts, rowstart, cursor, DEG, N);
    build_elist<<<eGrid, 256, 0, stream>>>(ei, cursor, elist, E);
    gather_ef<<<geGrid, 256, 0, stream>>>(elist, rowstart, ef, EFA, N);

    // ---- conv1 ----
    // h1 = relu(nf @ c1_pre_W + b)
    gemm_tiled<<<gemmGrid, 256, 0, stream>>>(nf, c1pW, c1pb, nullptr, A, N, 128, 7, 2);
    gather_h<<<ghGrid, 256, 0, stream>>>(elist, rowstart, A, B, N);
    // x1 = relu(deg*(h1@Wi + b_msg) + agg@Wj + aggef@We)
    gemm_tiled<<<gemmGrid, 256, 0, stream>>>(B,   c1mW + 128 * 128, nullptr, nullptr, C, N, 128, 7, 0);
    gemm_tiled<<<gemmGrid, 256, 0, stream>>>(EFA, c1mW + 256 * 128, nullptr, nullptr, C, N, 16,  4, 1);
    gemm_tiled<<<gemmGrid, 256, 0, stream>>>(A,   c1mW,             c1mb,    DEG,     C, N, 128, 7, 1 | 2);

    // ---- conv2 ----
    // h2 = relu(x1 @ c2_pre_W + b)
    gemm_tiled<<<gemmGrid, 256, 0, stream>>>(C, c2pW, c2pb, nullptr, A, N, 128, 7, 2);
    gather_h<<<ghGrid, 256, 0, stream>>>(elist, rowstart, A, B, N);
    // x2 = deg*(h2@Wi + b_msg) + agg@Wj + aggef@We   (no relu)
    gemm_tiled<<<gemmGrid, 256, 0, stream>>>(B,   c2mW + 128 * 128, nullptr, nullptr, C, N, 128, 7, 0);
    gemm_tiled<<<gemmGrid, 256, 0, stream>>>(EFA, c2mW + 256 * 128, nullptr, nullptr, C, N, 16,  4, 1);
    gemm_tiled<<<gemmGrid, 256, 0, stream>>>(A,   c2mW,             c2mb,    DEG,     C, N, 128, 7, 1);

    // ---- head ----
    head_kernel<<<headGrid, 256, 0, stream>>>(C, eli, lpW, lpb, out, Q);
}